// Round 1
// baseline (477.520 us; speedup 1.0000x reference)
//
#include <hip/hip_runtime.h>

#define C_   128
#define P_   4096
#define K3   384
#define CP   (C_*P_)
#define NB_  32

typedef __attribute__((ext_vector_type(8))) short short8;
typedef __attribute__((ext_vector_type(4))) float f32x4;

__device__ __forceinline__ short f2bf(float f) {
  union { float f; unsigned u; } v; v.f = f;
  unsigned r = v.u + 0x7fffu + ((v.u >> 16) & 1u);
  return (short)(r >> 16);
}
__device__ __forceinline__ float bf2f(short b) {
  union { unsigned u; float f; } v; v.u = ((unsigned)(unsigned short)b) << 16;
  return v.f;
}

// ---------------- E1: t5 = p5[h,w] * max3w(x) ----------------
__global__ __launch_bounds__(256) void t5_kernel(const float* __restrict__ x,
                                                 const float* __restrict__ p5,
                                                 short* __restrict__ t5) {
  int i = blockIdx.x * 256 + threadIdx.x;           // over N*C*P = 16.7M
  int p = i & (P_ - 1);
  int w = p & 63;
  float m0 = x[i];
  float a = (w >= 2) ? x[i - 2] : 0.f;              // zero-padding participates in max
  float b = (w < 62) ? x[i + 2] : 0.f;
  float t2 = fmaxf(fmaxf(a, m0), b);
  t5[i] = f2bf(p5[p] * t2);
}

// ---------------- G2: t6 = w6 @ shifted(t5); t7 = max(x, t6) ----------------
__global__ __launch_bounds__(256) void g2_kernel(const float* __restrict__ x,
                                                 const float* __restrict__ w6,
                                                 const short* __restrict__ t5,
                                                 short* __restrict__ t6,
                                                 short* __restrict__ t7) {
  int blk = blockIdx.x;
  int n = blk >> 5, pt = blk & 31;
  int p0 = pt * 128;
  int tid = threadIdx.x, lane = tid & 63, wv = tid >> 6;
  int wm = (wv & 1) * 64, wp = (wv >> 1) * 64;
  const float* xn = x + (size_t)n * CP;
  const short* t5n = t5 + (size_t)n * CP;
  __shared__ __align__(16) short As[4][128][8];
  __shared__ __align__(16) short Bs[4][128][8];
  f32x4 acc[4][4] = {};
  for (int ks = 0; ks < 12; ++ks) {
    int k0 = ks * 32;
    __syncthreads();
    // A: w6 flat [o][i*3+r] = w6[o*384 + k]
#pragma unroll
    for (int it = 0; it < 2; ++it) {
      int idx = tid + it * 256;
      int m = idx & 127, q = idx >> 7;
      const float* ar = w6 + m * K3 + k0 + q * 8;
      short8 v;
#pragma unroll
      for (int jj = 0; jj < 8; ++jj) v[jj] = f2bf(ar[jj]);
      *(short8*)(&As[q][m][0]) = v;
    }
    // B: B[k=(i,r)][p] = t5[i, p + 192*(r-1)] (h-shift, zero-pad)
#pragma unroll
    for (int it = 0; it < 2; ++it) {
      int idx = tid + it * 256;
      int pc = idx & 127, q = idx >> 7;
      int p = p0 + pc;
      short8 v;
#pragma unroll
      for (int jj = 0; jj < 8; ++jj) {
        int k = k0 + q * 8 + jj;
        int ii = k / 3, r = k - ii * 3;
        int pp = p + 192 * (r - 1);
        short val = 0;
        if (pp >= 0 && pp < P_) val = t5n[ii * P_ + pp];
        v[jj] = val;
      }
      *(short8*)(&Bs[q][pc][0]) = v;
    }
    __syncthreads();
    int row = lane & 15, q = lane >> 4;
    short8 a[4], b[4];
#pragma unroll
    for (int im = 0; im < 4; ++im) a[im] = *(const short8*)(&As[q][wm + im * 16 + row][0]);
#pragma unroll
    for (int ip = 0; ip < 4; ++ip) b[ip] = *(const short8*)(&Bs[q][wp + ip * 16 + row][0]);
#pragma unroll
    for (int im = 0; im < 4; ++im)
#pragma unroll
      for (int ip = 0; ip < 4; ++ip)
        acc[im][ip] = __builtin_amdgcn_mfma_f32_16x16x32_bf16(a[im], b[ip], acc[im][ip], 0, 0, 0);
  }
  int col = lane & 15, rq = lane >> 4;
#pragma unroll
  for (int im = 0; im < 4; ++im)
#pragma unroll
    for (int ip = 0; ip < 4; ++ip)
#pragma unroll
      for (int r = 0; r < 4; ++r) {
        int m = wm + im * 16 + rq * 4 + r;
        int p = p0 + wp + ip * 16 + col;
        float t6v = acc[im][ip][r];
        float xv = xn[m * P_ + p];
        size_t o = (size_t)n * CP + m * P_ + p;
        t6[o] = f2bf(t6v);
        t7[o] = f2bf(fmaxf(xv, t6v));
      }
}

// ---------------- G1: t3 = w3 @ t1 (t1 = w-shifted x) ----------------
__global__ __launch_bounds__(256) void g1_kernel(const float* __restrict__ x,
                                                 const float* __restrict__ w3,
                                                 short* __restrict__ t3) {
  int blk = blockIdx.x;
  int n = blk >> 5, pt = blk & 31;
  int p0 = pt * 128;
  int tid = threadIdx.x, lane = tid & 63, wv = tid >> 6;
  int wm = (wv & 1) * 64, wp = (wv >> 1) * 64;
  const float* xn = x + (size_t)n * CP;
  __shared__ __align__(16) short As[4][128][8];
  __shared__ __align__(16) short Bs[4][128][8];
  f32x4 acc[4][4] = {};
  for (int ks = 0; ks < 12; ++ks) {
    int k0 = ks * 32;
    __syncthreads();
#pragma unroll
    for (int it = 0; it < 2; ++it) {
      int idx = tid + it * 256;
      int m = idx & 127, q = idx >> 7;
      const float* ar = w3 + m * K3 + k0 + q * 8;
      short8 v;
#pragma unroll
      for (int jj = 0; jj < 8; ++jj) v[jj] = f2bf(ar[jj]);
      *(short8*)(&As[q][m][0]) = v;
    }
    // B: t1[k=(c,j)][p] = x[c, p + 2*(j-1)] (w-shift, zero-pad)
#pragma unroll
    for (int it = 0; it < 2; ++it) {
      int idx = tid + it * 256;
      int pc = idx & 127, q = idx >> 7;
      int p = p0 + pc;
      int w = p & 63;
      short8 v;
#pragma unroll
      for (int jj = 0; jj < 8; ++jj) {
        int k = k0 + q * 8 + jj;
        int c = k / 3, j = k - c * 3, d = 2 * (j - 1);
        int wd = w + d;
        float val = (wd >= 0 && wd < 64) ? xn[c * P_ + p + d] : 0.f;
        v[jj] = f2bf(val);
      }
      *(short8*)(&Bs[q][pc][0]) = v;
    }
    __syncthreads();
    int row = lane & 15, q = lane >> 4;
    short8 a[4], b[4];
#pragma unroll
    for (int im = 0; im < 4; ++im) a[im] = *(const short8*)(&As[q][wm + im * 16 + row][0]);
#pragma unroll
    for (int ip = 0; ip < 4; ++ip) b[ip] = *(const short8*)(&Bs[q][wp + ip * 16 + row][0]);
#pragma unroll
    for (int im = 0; im < 4; ++im)
#pragma unroll
      for (int ip = 0; ip < 4; ++ip)
        acc[im][ip] = __builtin_amdgcn_mfma_f32_16x16x32_bf16(a[im], b[ip], acc[im][ip], 0, 0, 0);
  }
  int col = lane & 15, rq = lane >> 4;
#pragma unroll
  for (int im = 0; im < 4; ++im)
#pragma unroll
    for (int ip = 0; ip < 4; ++ip)
#pragma unroll
      for (int r = 0; r < 4; ++r) {
        int m = wm + im * 16 + rq * 4 + r;
        int p = p0 + wp + ip * 16 + col;
        t3[(size_t)n * CP + m * P_ + p] = f2bf(acc[im][ip][r]);
      }
}

// ---------------- G3: t9_raw[c][k] += sum_p (p8[c]*t7[c,p]) * t1[k,p]  (split-K=4) ----------------
__global__ __launch_bounds__(256) void g3_kernel(const float* __restrict__ x,
                                                 const float* __restrict__ p8,
                                                 const short* __restrict__ t7,
                                                 float* __restrict__ t9) {
  int blk = blockIdx.x;
  int nb = blk % 3;
  int n = (blk / 3) & 31;
  int sk = blk / 96;
  int tid = threadIdx.x, lane = tid & 63, wv = tid >> 6;
  int wm = (wv & 1) * 64, wp = (wv >> 1) * 64;
  const float* xn = x + (size_t)n * CP;
  const short* t7n = t7 + (size_t)n * CP;
  __shared__ __align__(16) short As[4][128][8];
  __shared__ __align__(16) short Bs[4][128][8];
  f32x4 acc[4][4] = {};
  for (int ks = 0; ks < 32; ++ks) {
    int pp0 = sk * 1024 + ks * 32;
    __syncthreads();
    // A: rows c, K-dim is p: t8[c, pp0 + q*8 + jj]
#pragma unroll
    for (int it = 0; it < 2; ++it) {
      int idx = tid + it * 256;
      int c = idx & 127, q = idx >> 7;
      float sc = p8[c];
      const short* tr = t7n + c * P_ + pp0 + q * 8;
      short8 raw = *(const short8*)tr;
      short8 v;
#pragma unroll
      for (int jj = 0; jj < 8; ++jj) v[jj] = f2bf(sc * bf2f(raw[jj]));
      *(short8*)(&As[q][c][0]) = v;
    }
    // B: B[p][k] = t1[k, p] = x[c_k, p + 2*(j_k-1)]
#pragma unroll
    for (int it = 0; it < 2; ++it) {
      int idx = tid + it * 256;
      int kc = idx & 127, q = idx >> 7;
      int k = nb * 128 + kc;
      int c = k / 3, j = k - c * 3, d = 2 * (j - 1);
      const float* xr = xn + c * P_;
      int pb = pp0 + q * 8;
      short8 v;
#pragma unroll
      for (int jj = 0; jj < 8; ++jj) {
        int p = pb + jj, w = p & 63, wd = w + d;
        float val = (wd >= 0 && wd < 64) ? xr[p + d] : 0.f;
        v[jj] = f2bf(val);
      }
      *(short8*)(&Bs[q][kc][0]) = v;
    }
    __syncthreads();
    int row = lane & 15, q = lane >> 4;
    short8 a[4], b[4];
#pragma unroll
    for (int im = 0; im < 4; ++im) a[im] = *(const short8*)(&As[q][wm + im * 16 + row][0]);
#pragma unroll
    for (int ip = 0; ip < 4; ++ip) b[ip] = *(const short8*)(&Bs[q][wp + ip * 16 + row][0]);
#pragma unroll
    for (int im = 0; im < 4; ++im)
#pragma unroll
      for (int ip = 0; ip < 4; ++ip)
        acc[im][ip] = __builtin_amdgcn_mfma_f32_16x16x32_bf16(a[im], b[ip], acc[im][ip], 0, 0, 0);
  }
  int col = lane & 15, rq = lane >> 4;
#pragma unroll
  for (int im = 0; im < 4; ++im)
#pragma unroll
    for (int ip = 0; ip < 4; ++ip)
#pragma unroll
      for (int r = 0; r < 4; ++r) {
        int c = wm + im * 16 + rq * 4 + r;
        int k = nb * 128 + wp + ip * 16 + col;
        atomicAdd(&t9[(size_t)n * (C_ * K3) + c * K3 + k], acc[im][ip][r]);
      }
}

// ---------------- G4: out[c][p] = scale * sum_k t9[c][k] * t12[k][p] ----------------
__global__ __launch_bounds__(256) void g4_kernel(const float* __restrict__ x,
                                                 const float* __restrict__ p12,
                                                 const float* __restrict__ t9,
                                                 const short* __restrict__ t3,
                                                 const short* __restrict__ t6,
                                                 const short* __restrict__ t7,
                                                 float* __restrict__ out) {
  int blk = blockIdx.x;
  int n = blk >> 5, pt = blk & 31;
  int p0 = pt * 128;
  int tid = threadIdx.x, lane = tid & 63, wv = tid >> 6;
  int wm = (wv & 1) * 64, wp = (wv >> 1) * 64;
  const float* xn = x + (size_t)n * CP;
  const short* t3n = t3 + (size_t)n * CP;
  const short* t6n = t6 + (size_t)n * CP;
  const short* t7n = t7 + (size_t)n * CP;
  const float* t9n = t9 + (size_t)n * (C_ * K3);
  __shared__ __align__(16) short As[4][128][8];
  __shared__ __align__(16) short Bs[4][128][8];
  f32x4 acc[4][4] = {};
  for (int ks = 0; ks < 12; ++ks) {
    int k0 = ks * 32;
    __syncthreads();
    // A: raw t9 (scale folded into epilogue)
#pragma unroll
    for (int it = 0; it < 2; ++it) {
      int idx = tid + it * 256;
      int m = idx & 127, q = idx >> 7;
      const float* ar = t9n + m * K3 + k0 + q * 8;
      short8 v;
#pragma unroll
      for (int jj = 0; jj < 8; ++jj) v[jj] = f2bf(ar[jj]);
      *(short8*)(&As[q][m][0]) = v;
    }
    // B: t12[k=(i,j)][p] = p12[j,h] * max(t6[i,p], t7[i,p] + max(t3[i,p], t1[(i,j),p]))
#pragma unroll
    for (int it = 0; it < 2; ++it) {
      int idx = tid + it * 256;
      int pc = idx & 127, q = idx >> 7;
      int p = p0 + pc;
      int w = p & 63, h = p >> 6;
      short8 v;
#pragma unroll
      for (int jj = 0; jj < 8; ++jj) {
        int k = k0 + q * 8 + jj;
        int ii = k / 3, j = k - ii * 3, d = 2 * (j - 1);
        int wd = w + d;
        float xv = (wd >= 0 && wd < 64) ? xn[ii * P_ + p + d] : 0.f;
        int o = ii * P_ + p;
        float t3v = bf2f(t3n[o]);
        float t6v = bf2f(t6n[o]);
        float t7v = bf2f(t7n[o]);
        float t11 = fmaxf(t6v, t7v + fmaxf(t3v, xv));
        v[jj] = f2bf(p12[j * 64 + h] * t11);
      }
      *(short8*)(&Bs[q][pc][0]) = v;
    }
    __syncthreads();
    int row = lane & 15, q = lane >> 4;
    short8 a[4], b[4];
#pragma unroll
    for (int im = 0; im < 4; ++im) a[im] = *(const short8*)(&As[q][wm + im * 16 + row][0]);
#pragma unroll
    for (int ip = 0; ip < 4; ++ip) b[ip] = *(const short8*)(&Bs[q][wp + ip * 16 + row][0]);
#pragma unroll
    for (int im = 0; im < 4; ++im)
#pragma unroll
      for (int ip = 0; ip < 4; ++ip)
        acc[im][ip] = __builtin_amdgcn_mfma_f32_16x16x32_bf16(a[im], b[ip], acc[im][ip], 0, 0, 0);
  }
  const float SCALE = 1.0f / (64.0f * sqrtf(384.0f));   // t9 /64 and t13 /sqrt(3c)
  int col = lane & 15, rq = lane >> 4;
#pragma unroll
  for (int im = 0; im < 4; ++im)
#pragma unroll
    for (int ip = 0; ip < 4; ++ip)
#pragma unroll
      for (int r = 0; r < 4; ++r) {
        int m = wm + im * 16 + rq * 4 + r;
        int p = p0 + wp + ip * 16 + col;
        out[(size_t)n * CP + m * P_ + p] = acc[im][ip][r] * SCALE;
      }
}

extern "C" void kernel_launch(void* const* d_in, const int* in_sizes, int n_in,
                              void* d_out, int out_size, void* d_ws, size_t ws_size,
                              hipStream_t stream) {
  const float* x   = (const float*)d_in[0];
  const float* w3  = (const float*)d_in[1];
  const float* p5  = (const float*)d_in[2];
  const float* w6  = (const float*)d_in[3];
  const float* p8  = (const float*)d_in[4];
  const float* p12 = (const float*)d_in[5];
  float* out = (float*)d_out;

  char* ws = (char*)d_ws;
  const size_t RB = (size_t)NB_ * CP * 2;       // 33,554,432 B per bf16 tensor
  short* t5t3 = (short*)(ws);                   // t5 first, reused as t3 after g2
  short* t6   = (short*)(ws + RB);
  short* t7   = (short*)(ws + 2 * RB);
  float* t9   = (float*)(ws + 3 * RB);          // 32*128*384 fp32 = 6.29 MB

  hipMemsetAsync(t9, 0, (size_t)NB_ * C_ * K3 * sizeof(float), stream);
  t5_kernel<<<65536, 256, 0, stream>>>(x, p5, t5t3);
  g2_kernel<<<1024, 256, 0, stream>>>(x, w6, t5t3, t6, t7);   // consumes t5
  g1_kernel<<<1024, 256, 0, stream>>>(x, w3, t5t3);           // overwrites region with t3
  g3_kernel<<<384, 256, 0, stream>>>(x, p8, t7, t9);
  g4_kernel<<<1024, 256, 0, stream>>>(x, p12, t9, t5t3, t6, t7, out);
}